// Round 1
// baseline (549.790 us; speedup 1.0000x reference)
//
#include <hip/hip_runtime.h>

typedef unsigned short ushort_t;
typedef __attribute__((ext_vector_type(8))) short bf16x8;
typedef __attribute__((ext_vector_type(4))) float f32x4;

#define LOG2E 1.44269504088896340736f

__device__ inline ushort_t f2bf(float f) {
    unsigned int u = __float_as_uint(f);
    unsigned int r = (u + 0x7FFFu + ((u >> 16) & 1u)) >> 16;
    return (ushort_t)r;
}

__device__ inline float red_max16(float v) {
    v = fmaxf(v, __shfl_xor(v, 1));
    v = fmaxf(v, __shfl_xor(v, 2));
    v = fmaxf(v, __shfl_xor(v, 4));
    v = fmaxf(v, __shfl_xor(v, 8));
    return v;
}
__device__ inline float red_sum16(float v) {
    v += __shfl_xor(v, 1);
    v += __shfl_xor(v, 2);
    v += __shfl_xor(v, 4);
    v += __shfl_xor(v, 8);
    return v;
}

// ---------------- transpose + cast: W[K,N] f32 -> Wt[N,K] bf16 (1024x1024) ----
__global__ __launch_bounds__(256) void transpose_cast(const float* __restrict__ W,
                                                      ushort_t* __restrict__ Wt) {
    __shared__ float tile[32][33];
    const int bx = blockIdx.x & 31;   // n tile
    const int by = blockIdx.x >> 5;   // k tile
    const int n0 = bx * 32, k0 = by * 32;
    const int tx = threadIdx.x & 31, ty = threadIdx.x >> 5;  // ty 0..7
#pragma unroll
    for (int i = 0; i < 4; ++i) {
        int r = ty + i * 8;
        tile[r][tx] = W[(k0 + r) * 1024 + n0 + tx];
    }
    __syncthreads();
#pragma unroll
    for (int i = 0; i < 4; ++i) {
        int r = ty + i * 8;  // n offset
        Wt[(n0 + r) * 1024 + k0 + tx] = f2bf(tile[tx][r]);
    }
}

// ---------------- GEMM: C[M=8192, N=1024] = A[M,1024] @ Wt[N,1024]^T + bias ---
// AF32: A operand is fp32 (converted to bf16 while staging); else bf16.
// OMODE 0: write bf16 split-heads [B,H,S,D]; OMODE 1: write f32 [M,N].
template <int AF32, int OMODE>
__global__ __launch_bounds__(256) void gemm_bt(const void* __restrict__ Ap,
                                               const ushort_t* __restrict__ Bt,
                                               const float* __restrict__ bias,
                                               void* __restrict__ out) {
    __shared__ alignas(16) ushort_t As[128 * 72];
    __shared__ alignas(16) ushort_t Bs[128 * 72];
    const int t = threadIdx.x;
    const int lane = t & 63, w = t >> 6;
    const int q = lane & 15, g = lane >> 4;
    const int wr = w >> 1, wc = w & 1;
    const int bm = blockIdx.x & 63, bn = blockIdx.x >> 6;
    const int m0 = bm * 128, n0 = bn * 128;

    f32x4 acc[4][4];
#pragma unroll
    for (int i = 0; i < 4; ++i)
#pragma unroll
        for (int j = 0; j < 4; ++j) acc[i][j] = (f32x4){0.f, 0.f, 0.f, 0.f};

    for (int k0 = 0; k0 < 1024; k0 += 64) {
        __syncthreads();
#pragma unroll
        for (int it = 0; it < 4; ++it) {
            int tt = t + it * 256;
            int row = tt >> 3;
            int col = (tt & 7) * 8;
            if (AF32) {
                const float* A = (const float*)Ap;
                float4 v0 = *(const float4*)&A[(size_t)(m0 + row) * 1024 + k0 + col];
                float4 v1 = *(const float4*)&A[(size_t)(m0 + row) * 1024 + k0 + col + 4];
                bf16x8 b;
                b[0] = (short)f2bf(v0.x); b[1] = (short)f2bf(v0.y);
                b[2] = (short)f2bf(v0.z); b[3] = (short)f2bf(v0.w);
                b[4] = (short)f2bf(v1.x); b[5] = (short)f2bf(v1.y);
                b[6] = (short)f2bf(v1.z); b[7] = (short)f2bf(v1.w);
                *(bf16x8*)&As[row * 72 + col] = b;
            } else {
                const ushort_t* A = (const ushort_t*)Ap;
                *(bf16x8*)&As[row * 72 + col] =
                    *(const bf16x8*)&A[(size_t)(m0 + row) * 1024 + k0 + col];
            }
            *(bf16x8*)&Bs[row * 72 + col] =
                *(const bf16x8*)&Bt[(size_t)(n0 + row) * 1024 + k0 + col];
        }
        __syncthreads();
#pragma unroll
        for (int kt = 0; kt < 2; ++kt) {
            bf16x8 af[4], bfr[4];
#pragma unroll
            for (int mt = 0; mt < 4; ++mt)
                af[mt] = *(const bf16x8*)&As[(wr * 64 + mt * 16 + q) * 72 + kt * 32 + g * 8];
#pragma unroll
            for (int nt = 0; nt < 4; ++nt)
                bfr[nt] = *(const bf16x8*)&Bs[(wc * 64 + nt * 16 + q) * 72 + kt * 32 + g * 8];
#pragma unroll
            for (int mt = 0; mt < 4; ++mt)
#pragma unroll
                for (int nt = 0; nt < 4; ++nt)
                    acc[mt][nt] = __builtin_amdgcn_mfma_f32_16x16x32_bf16(
                        af[mt], bfr[nt], acc[mt][nt], 0, 0, 0);
        }
    }

#pragma unroll
    for (int mt = 0; mt < 4; ++mt) {
#pragma unroll
        for (int nt = 0; nt < 4; ++nt) {
#pragma unroll
            for (int r = 0; r < 4; ++r) {
                int grow = m0 + wr * 64 + mt * 16 + g * 4 + r;  // 0..8191
                int col = n0 + wc * 64 + nt * 16 + q;           // 0..1023
                float v = acc[mt][nt][r] + bias[col];
                if (OMODE == 0) {
                    int b = grow >> 11, s = grow & 2047;
                    int h = col >> 6, d = col & 63;
                    ((ushort_t*)out)[(((size_t)(b * 16 + h) * 2048 + s) * 64) + d] = f2bf(v);
                } else {
                    ((float*)out)[(size_t)grow * 1024 + col] = v;
                }
            }
        }
    }
}

// ---------------- flash attention over [B,H,S,D] bf16, out [B,S,E] bf16 ------
__global__ __launch_bounds__(256) void attn_kernel(const ushort_t* __restrict__ Qp,
                                                   const ushort_t* __restrict__ Kp,
                                                   const ushort_t* __restrict__ Vp,
                                                   ushort_t* __restrict__ Oa) {
    __shared__ alignas(16) ushort_t VT[4][64 * 40];  // per-wave V^T tile [d=64][kv=32] pad 40
    __shared__ alignas(16) ushort_t PL[4][16 * 40];  // per-wave P tile [q=16][kv=32] pad 40

    const int t = threadIdx.x, lane = t & 63, w = t >> 6;
    const int q = lane & 15, g = lane >> 4;
    const int pair = blockIdx.x >> 5;                 // b*16 + h
    const int qbase = (blockIdx.x & 31) * 64 + w * 16;

    const ushort_t* Qh = Qp + (size_t)pair * 2048 * 64;
    const ushort_t* Kh = Kp + (size_t)pair * 2048 * 64;
    const ushort_t* Vh = Vp + (size_t)pair * 2048 * 64;
    ushort_t* vt = VT[w];
    ushort_t* pl = PL[w];

    bf16x8 aq[2];
    aq[0] = *(const bf16x8*)&Qh[(size_t)(qbase + q) * 64 + g * 8];
    aq[1] = *(const bf16x8*)&Qh[(size_t)(qbase + q) * 64 + 32 + g * 8];

    f32x4 o[4];
#pragma unroll
    for (int dt = 0; dt < 4; ++dt) o[dt] = (f32x4){0.f, 0.f, 0.f, 0.f};
    float m_[4], l_[4];
#pragma unroll
    for (int r = 0; r < 4; ++r) { m_[r] = -INFINITY; l_[r] = 0.f; }

    const int vrow = lane >> 1;         // kv row staged by this lane
    const int vd0 = (lane & 1) * 32;    // d half

    for (int kv0 = 0; kv0 < 2048; kv0 += 32) {
        // --- S tile [16q, 32kv] = Q Kt (scaled later) ---
        f32x4 sc[2];
        sc[0] = (f32x4){0.f, 0.f, 0.f, 0.f};
        sc[1] = (f32x4){0.f, 0.f, 0.f, 0.f};
#pragma unroll
        for (int c = 0; c < 2; ++c) {
            bf16x8 bk0 = *(const bf16x8*)&Kh[(size_t)(kv0 + c * 16 + q) * 64 + g * 8];
            bf16x8 bk1 = *(const bf16x8*)&Kh[(size_t)(kv0 + c * 16 + q) * 64 + 32 + g * 8];
            sc[c] = __builtin_amdgcn_mfma_f32_16x16x32_bf16(aq[0], bk0, sc[c], 0, 0, 0);
            sc[c] = __builtin_amdgcn_mfma_f32_16x16x32_bf16(aq[1], bk1, sc[c], 0, 0, 0);
        }
        // --- stage V^T into LDS ---
#pragma unroll
        for (int i = 0; i < 4; ++i) {
            bf16x8 v = *(const bf16x8*)&Vh[(size_t)(kv0 + vrow) * 64 + vd0 + i * 8];
#pragma unroll
            for (int j = 0; j < 8; ++j)
                vt[(vd0 + i * 8 + j) * 40 + vrow] = (ushort_t)v[j];
        }
        // --- online softmax ---
#pragma unroll
        for (int r = 0; r < 4; ++r) {
            float s0 = sc[0][r] * 0.125f;
            float s1 = sc[1][r] * 0.125f;
            float tm = red_max16(fmaxf(s0, s1));
            float mn = fmaxf(m_[r], tm);
            float corr = exp2f((m_[r] - mn) * LOG2E);
            float p0 = exp2f((s0 - mn) * LOG2E);
            float p1 = exp2f((s1 - mn) * LOG2E);
            float ts = red_sum16(p0 + p1);
            l_[r] = l_[r] * corr + ts;
            m_[r] = mn;
#pragma unroll
            for (int dt = 0; dt < 4; ++dt) o[dt][r] *= corr;
            pl[(g * 4 + r) * 40 + q] = f2bf(p0);
            pl[(g * 4 + r) * 40 + 16 + q] = f2bf(p1);
        }
        __syncthreads();
        // --- PV ---
        bf16x8 ap = *(const bf16x8*)&pl[q * 40 + g * 8];
#pragma unroll
        for (int dt = 0; dt < 4; ++dt) {
            bf16x8 bv = *(const bf16x8*)&vt[(dt * 16 + q) * 40 + g * 8];
            o[dt] = __builtin_amdgcn_mfma_f32_16x16x32_bf16(ap, bv, o[dt], 0, 0, 0);
        }
        __syncthreads();
    }

    const int b = pair >> 4, h = pair & 15;
#pragma unroll
    for (int dt = 0; dt < 4; ++dt) {
#pragma unroll
        for (int r = 0; r < 4; ++r) {
            int s = qbase + g * 4 + r;
            float v = o[dt][r] / l_[r];
            Oa[((size_t)(b * 2048 + s)) * 1024 + h * 64 + dt * 16 + q] = f2bf(v);
        }
    }
}

extern "C" void kernel_launch(void* const* d_in, const int* in_sizes, int n_in,
                              void* d_out, int out_size, void* d_ws, size_t ws_size,
                              hipStream_t stream) {
    const float* query = (const float*)d_in[0];
    const float* key_ = (const float*)d_in[1];
    const float* value = (const float*)d_in[2];
    const float* Wq = (const float*)d_in[3];
    const float* bq = (const float*)d_in[4];
    const float* Wk = (const float*)d_in[5];
    const float* bk = (const float*)d_in[6];
    const float* Wv = (const float*)d_in[7];
    const float* bv = (const float*)d_in[8];
    const float* Wo = (const float*)d_in[9];
    const float* bo = (const float*)d_in[10];
    float* out = (float*)d_out;

    char* ws = (char*)d_ws;
    ushort_t* Wqt = (ushort_t*)(ws + 0);
    ushort_t* Wkt = (ushort_t*)(ws + 2097152);
    ushort_t* Wvt = (ushort_t*)(ws + 4194304);
    ushort_t* Wot = (ushort_t*)(ws + 6291456);
    ushort_t* Qp = (ushort_t*)(ws + 8388608);
    ushort_t* Kp = (ushort_t*)(ws + 25165824);
    ushort_t* Vp = (ushort_t*)(ws + 41943040);
    ushort_t* Oa = (ushort_t*)(ws + 58720256);
    // total ws use: 75497472 bytes

    transpose_cast<<<1024, 256, 0, stream>>>(Wq, Wqt);
    transpose_cast<<<1024, 256, 0, stream>>>(Wk, Wkt);
    transpose_cast<<<1024, 256, 0, stream>>>(Wv, Wvt);
    transpose_cast<<<1024, 256, 0, stream>>>(Wo, Wot);

    gemm_bt<1, 0><<<512, 256, 0, stream>>>((const void*)query, Wqt, bq, (void*)Qp);
    gemm_bt<1, 0><<<512, 256, 0, stream>>>((const void*)key_, Wkt, bk, (void*)Kp);
    gemm_bt<1, 0><<<512, 256, 0, stream>>>((const void*)value, Wvt, bv, (void*)Vp);

    attn_kernel<<<2048, 256, 0, stream>>>(Qp, Kp, Vp, Oa);

    gemm_bt<0, 1><<<512, 256, 0, stream>>>((const void*)Oa, Wot, bo, (void*)out);
}